// Round 3
// baseline (192.748 us; speedup 1.0000x reference)
//
#include <hip/hip_runtime.h>
#include <hip/hip_bf16.h>

typedef short short8 __attribute__((ext_vector_type(8)));
typedef float float4v __attribute__((ext_vector_type(4)));

#define NIMG 32
#define CIN 256
#define COUT 256
#define HH 56
#define WW 56
#define HP 58
#define WP 58
#define PIXIMG (HH * WW)          /* 3136 */
#define TOTPIX (NIMG * PIXIMG)    /* 100352 */
#define OUTSTRIDE_N (COUT * PIXIMG)

static constexpr size_t XT_ELEMS = (size_t)NIMG * HP * WP * CIN; // bf16
static constexpr size_t WT_ELEMS = (size_t)9 * COUT * CIN;       // bf16

// fp32 -> bf16 bits, round-to-nearest-even (finite inputs only)
static __device__ __forceinline__ unsigned short f2bf(float f) {
    unsigned int u = __builtin_bit_cast(unsigned int, f);
    u = (u + 0x7fffu + ((u >> 16) & 1u)) >> 16;
    return (unsigned short)u;
}

// async global(16B/lane) -> LDS (wave-uniform base + lane*16)
static __device__ __forceinline__ void gl16(const unsigned short* g, char* l) {
    __builtin_amdgcn_global_load_lds(
        (const __attribute__((address_space(1))) void*)g,
        (__attribute__((address_space(3))) void*)l, 16, 0, 0);
}

// ---------------------------------------------------------------------------
// x (NCHW fp32) -> x_t[n][h'][w'][ic] bf16, padded; halo zeroed in-kernel.
// One block per (n, padded row h', 64-ic slice).
// ---------------------------------------------------------------------------
__global__ __launch_bounds__(256) void k_transpose(const float* __restrict__ x,
                                                   unsigned short* __restrict__ xt) {
    int b   = blockIdx.x;
    int icb = b & 3;
    int hp  = (b >> 2) % HP;    // padded output row 0..57
    int n   = b / (4 * HP);
    unsigned short* rowb = xt + ((size_t)(n * HP + hp) * WP) * CIN + icb * 64;
    int t = threadIdx.x;

    if (hp == 0 || hp == HP - 1) {
        // zero whole padded row slice: 58 w-positions x 64 ic
        for (int idx = t; idx < WP * 8; idx += 256) {
            int wq = idx >> 3, q = idx & 7;
            *(uint4*)(rowb + (size_t)wq * CIN + q * 8) = (uint4){0, 0, 0, 0};
        }
        return;
    }
    int h = hp - 1;
    __shared__ __align__(16) char lds[64 * 128]; // [w 64][ic 64] bf16, swizzled
    int w = t & 63, icl0 = t >> 6;
    if (w < WW) {
        const float* src = x + ((size_t)(n * CIN + icb * 64 + icl0) * HH + h) * WW + w;
#pragma unroll
        for (int j = 0; j < 16; ++j) {
            float v = src[(size_t)(j * 4) * PIXIMG];
            int icl = icl0 + j * 4;
            *(unsigned short*)(lds + w * 128 + ((icl * 2) ^ ((w & 7) << 4))) = f2bf(v);
        }
    }
    __syncthreads();
    int ic4 = t & 15, wr = t >> 4;
    unsigned short* dst = rowb + (size_t)CIN + ic4 * 4; // w'=1 base
#pragma unroll
    for (int p = 0; p < 4; ++p) {
        int w2 = wr + p * 16;
        if (w2 < WW) {
            uint2 v = *(const uint2*)(lds + w2 * 128 + ((ic4 * 8) ^ ((w2 & 7) << 4)));
            *(uint2*)(dst + (size_t)w2 * CIN) = v;
        }
    }
    if (t < 32) { // zero w'=0 and w'=57 columns
        int col = (t >> 4) * (WP - 1);
        *(uint2*)(rowb + (size_t)col * CIN + (t & 15) * 4) = (uint2){0, 0};
    }
}

// ---------------------------------------------------------------------------
// wt[tap][oc][ic] = bf16(weight * mask)
// ---------------------------------------------------------------------------
__global__ __launch_bounds__(256) void k_prepw(const float* __restrict__ wgt,
                                               const float* __restrict__ msk,
                                               unsigned short* __restrict__ wt) {
    int t = blockIdx.x * 256 + threadIdx.x; // t = oc*256 + ic
    const float* wp = wgt + (size_t)t * 9;
    const float* mp = msk + (size_t)t * 9;
#pragma unroll
    for (int tap = 0; tap < 9; ++tap)
        wt[(size_t)tap * (COUT * CIN) + t] = f2bf(wp[tap] * mp[tap]);
}

// K-step s (0..35) -> source offsets. tap = s>>2, ic-block = s&3.
static __device__ __forceinline__ int aofs(int s) {
    return ((s >> 2) << 16) + ((s & 3) << 6);
}
static __device__ __forceinline__ int bofs(int s) {
    int tap = s >> 2, dh = (tap * 86) >> 8, dw = tap - dh * 3;
    return (dh * WP + dw) * CIN + ((s & 3) << 6);
}

// ---------------------------------------------------------------------------
// Main conv: 9 shifted GEMMs as one K=2304 GEMM, 256x256 tile, 8-phase
// schedule (T3+T4 counted vmcnt + T5 setprio). 512 threads = 8 waves (2Mx4N),
// wave tile 128 oc x 64 pix, BK=64, 36 K-steps = 18 iterations x 2 tiles.
// LDS slots: slot s @ s*65536: A0@0 A1@16384 B0@32768 B1@49152 (16KB regions,
// [128 rows][64 ic] bf16, XOR-swizzled via pre-swizzled global sources).
// ---------------------------------------------------------------------------
__global__ __launch_bounds__(512, 2) void k_conv(const unsigned short* __restrict__ xt,
                                                 const unsigned short* __restrict__ wt,
                                                 float* __restrict__ out) {
    __shared__ __align__(16) char lds[131072];

    const int t    = threadIdx.x;
    const int lane = t & 63;
    const int wid  = t >> 6;
    const int wm   = wid >> 2;  // 0..1 : 128-oc half
    const int wn   = wid & 3;   // 0..3 : 64-pix quarter

    // XCD-aware swizzle: 392 blocks = 8 XCDs x 49
    const int b0    = blockIdx.x;
    const int ptile = (b0 & 7) * 49 + (b0 >> 3);

    // ---- staging addressing (pre-swizzled global sources, linear LDS dest) ----
    const int rl  = lane >> 3;                 // row-within-8 = row&7 at dest
    const int sc  = ((lane & 7) ^ rl) * 8;     // inverse-swizzled src col (elems)
    const size_t aSrc = (size_t)(wid * 8 + rl) * CIN + sc;
    const unsigned short* bS[4];
#pragma unroll
    for (int j = 0; j < 4; ++j) {
        int pg  = ptile * 256 + j * 64 + wid * 8 + rl;
        int n   = pg / PIXIMG;
        int rem = pg - n * PIXIMG;
        int h   = rem / WW, w = rem - h * WW;
        bS[j] = xt + ((size_t)((n * HP + h) * WP + w)) * CIN + sc;
    }
    char* const ldsDst = lds + wid * 1024;

#define STG_A(S, H, I, AOFF) \
    gl16(wt + (AOFF) + (size_t)((H) * 32768 + (I) * 16384) + aSrc, \
         ldsDst + (S) * 65536 + (H) * 16384 + (I) * 8192)
#define STG_B(S, H, I, BOFF) \
    gl16(bS[(H) * 2 + (I)] + (BOFF), \
         ldsDst + (S) * 65536 + 32768 + (H) * 16384 + (I) * 8192)

    // ---- fragment read offsets ----
    const int l15 = lane & 15;
    const int lg  = lane >> 4;
    const int aRd = wm * 16384 + l15 * 128;
    const int bRd = 32768 + (wn >> 1) * 16384 + ((wn & 1) * 64 + l15) * 128;
    int cO[2];
    cO[0] = (lg * 16) ^ ((l15 & 7) << 4);
    cO[1] = (64 + lg * 16) ^ ((l15 & 7) << 4);

#define LD_A(AF, S, MBASE)                                                   \
    _Pragma("unroll") for (int mi_ = 0; mi_ < 4; ++mi_)                      \
    _Pragma("unroll") for (int kk_ = 0; kk_ < 2; ++kk_)                      \
        AF[mi_][kk_] = *(const short8*)(lds + (S) * 65536 + aRd +            \
                                        ((MBASE) + mi_) * 2048 + cO[kk_]);
#define LD_B(BF, S, NBASE)                                                   \
    _Pragma("unroll") for (int ni_ = 0; ni_ < 2; ++ni_)                      \
    _Pragma("unroll") for (int kk_ = 0; kk_ < 2; ++kk_)                      \
        BF[ni_][kk_] = *(const short8*)(lds + (S) * 65536 + bRd +            \
                                        ((NBASE) + ni_) * 2048 + cO[kk_]);

#define BARRIER do { asm volatile("s_barrier" ::: "memory");                 \
                     __builtin_amdgcn_sched_barrier(0); } while (0)
#define VMW2 asm volatile("s_waitcnt vmcnt(2)" ::: "memory")
#define VMW0 asm volatile("s_waitcnt vmcnt(0)" ::: "memory")

#define QUAD(MB, NB, AF, BF) do {                                            \
    __builtin_amdgcn_s_setprio(1);                                           \
    _Pragma("unroll") for (int kk_ = 0; kk_ < 2; ++kk_)                      \
    _Pragma("unroll") for (int mi_ = 0; mi_ < 4; ++mi_)                      \
    _Pragma("unroll") for (int ni_ = 0; ni_ < 2; ++ni_)                      \
        acc[(MB) + mi_][(NB) + ni_] = __builtin_amdgcn_mfma_f32_16x16x32_bf16( \
            AF[mi_][kk_], BF[ni_][kk_], acc[(MB) + mi_][(NB) + ni_], 0, 0, 0); \
    __builtin_amdgcn_s_setprio(0);                                           \
} while (0)

    float4v acc[8][4];
#pragma unroll
    for (int i = 0; i < 8; ++i)
#pragma unroll
        for (int j = 0; j < 4; ++j)
            acc[i][j] = (float4v){0.f, 0.f, 0.f, 0.f};

    // ---- prologue: tile0 -> slot0 (8 issues), tile1 A.hi -> slot1 (2) ----
    STG_A(0, 0, 0, 0); STG_A(0, 0, 1, 0); STG_A(0, 1, 0, 0); STG_A(0, 1, 1, 0);
    STG_B(0, 0, 0, 0); STG_B(0, 0, 1, 0); STG_B(0, 1, 0, 0); STG_B(0, 1, 1, 0);
    {
        const int a1 = aofs(1);
        STG_A(1, 0, 1, a1); STG_A(1, 1, 1, a1);
    }
    VMW2; BARRIER;

    // ---- main loop: 18 iterations x 2 K-tiles, 8 phases each ----
#pragma unroll 1
    for (int it = 0; it < 18; ++it) {
        const int sO  = 2 * it + 1;
        const int sE2 = (it < 17) ? 2 * it + 2 : 0; // wrap: landed, never read
        const int sO2 = (it < 17) ? 2 * it + 3 : 1;
        const int aO1 = aofs(sO),  bO1 = bofs(sO);
        const int aO2 = aofs(sE2), bO2 = bofs(sE2);
        const int aO3 = aofs(sO2);

        short8 afl[4][2], afh[4][2], bfl[2][2], bfh[2][2];

        // ph1: read slot0 A.lo+B.lo; stage slot1 B0 <- sO; Q0
        LD_A(afl, 0, 0); LD_B(bfl, 0, 0);
        STG_B(1, 0, 0, bO1); STG_B(1, 0, 1, bO1);
        BARRIER; QUAD(0, 0, afl, bfl); BARRIER;
        // ph2: read slot0 B.hi; stage slot1 B1 <- sO; Q1
        LD_B(bfh, 0, 2);
        STG_B(1, 1, 0, bO1); STG_B(1, 1, 1, bO1);
        BARRIER; QUAD(0, 2, afl, bfh); BARRIER;
        // ph3: read slot0 A.hi; stage slot1 A0.lo+A1.lo <- sO; Q2
        LD_A(afh, 0, 4);
        STG_A(1, 0, 0, aO1); STG_A(1, 1, 0, aO1);
        BARRIER; QUAD(4, 2, afh, bfh); BARRIER;
        // ph4: stage slot0 A0.hi+A1.hi <- sE2; vmcnt(2); Q3
        STG_A(0, 0, 1, aO2); STG_A(0, 1, 1, aO2);
        VMW2; BARRIER; QUAD(4, 0, afh, bfl); BARRIER;
        // ph5: read slot1 A.lo+B.lo; stage slot0 B0 <- sE2; Q0
        LD_A(afl, 1, 0); LD_B(bfl, 1, 0);
        STG_B(0, 0, 0, bO2); STG_B(0, 0, 1, bO2);
        BARRIER; QUAD(0, 0, afl, bfl); BARRIER;
        // ph6: read slot1 B.hi; stage slot0 B1 <- sE2; Q1
        LD_B(bfh, 1, 2);
        STG_B(0, 1, 0, bO2); STG_B(0, 1, 1, bO2);
        BARRIER; QUAD(0, 2, afl, bfh); BARRIER;
        // ph7: read slot1 A.hi; stage slot0 A0.lo+A1.lo <- sE2; Q2
        LD_A(afh, 1, 4);
        STG_A(0, 0, 0, aO2); STG_A(0, 1, 0, aO2);
        BARRIER; QUAD(4, 2, afh, bfh); BARRIER;
        // ph8: stage slot1 A0.hi+A1.hi <- sO2; vmcnt(2); Q3
        STG_A(1, 0, 1, aO3); STG_A(1, 1, 1, aO3);
        VMW2; BARRIER; QUAD(4, 0, afh, bfl); BARRIER;
    }
#undef STG_A
#undef STG_B
#undef LD_A
#undef LD_B
#undef QUAD

    // ---- epilogue: drain async stages, LDS-transpose, coalesced stores ----
    VMW0;
    __syncthreads();
    float* ep = (float*)lds; // chunk: [128 oc][256 pix] f32, XOR-swizzled
#pragma unroll 1
    for (int c = 0; c < 2; ++c) {
        if (wm == c) {
#pragma unroll
            for (int mi = 0; mi < 8; ++mi)
#pragma unroll
                for (int ni = 0; ni < 4; ++ni)
#pragma unroll
                    for (int r = 0; r < 4; ++r) {
                        int row = mi * 16 + lg * 4 + r;
                        int pix = wn * 64 + ni * 16 + l15;
                        ep[row * 256 + (pix ^ ((row & 7) << 2))] = acc[mi][ni][r];
                    }
        }
        __syncthreads();
        const int row0 = t >> 6;
        const int c16  = t & 63;
#pragma unroll
        for (int p = 0; p < 16; ++p) {
            int row = p * 8 + row0;
            float4v v = *(const float4v*)&ep[row * 256 + ((c16 * 4) ^ ((row & 7) << 2))];
            int oc  = c * 128 + row;
            int pg  = ptile * 256 + c16 * 4;
            int n2  = pg / PIXIMG;
            int rem = pg - n2 * PIXIMG; // 3136%4==0: float4 stays in-image
            *(float4v*)(out + (size_t)n2 * OUTSTRIDE_N + (size_t)oc * PIXIMG + rem) = v;
        }
        if (c == 0) __syncthreads();
    }
}

// ---------------------------------------------------------------------------
// Fallback (ws too small): direct fp32 conv, slow but correct
// ---------------------------------------------------------------------------
__global__ __launch_bounds__(256) void k_naive(const float* __restrict__ x,
                                               const float* __restrict__ wg,
                                               const float* __restrict__ mk,
                                               float* __restrict__ out, int total) {
    int idx = blockIdx.x * 256 + threadIdx.x;
    if (idx >= total) return;
    int w  = idx % WW;
    int h  = (idx / WW) % HH;
    int oc = (idx / PIXIMG) % COUT;
    int n  = idx / (COUT * PIXIMG);
    float s = 0.f;
    for (int ic = 0; ic < CIN; ++ic) {
        const float* xp = x + (size_t)(n * CIN + ic) * PIXIMG;
        const float* wp = wg + (size_t)(oc * CIN + ic) * 9;
        const float* mp = mk + (size_t)(oc * CIN + ic) * 9;
#pragma unroll
        for (int kh = 0; kh < 3; ++kh) {
            int hy = h + kh - 1;
            if ((unsigned)hy >= HH) continue;
#pragma unroll
            for (int kw = 0; kw < 3; ++kw) {
                int wx = w + kw - 1;
                if ((unsigned)wx >= WW) continue;
                s += xp[hy * WW + wx] * wp[kh * 3 + kw] * mp[kh * 3 + kw];
            }
        }
    }
    out[idx] = s;
}

extern "C" void kernel_launch(void* const* d_in, const int* in_sizes, int n_in,
                              void* d_out, int out_size, void* d_ws, size_t ws_size,
                              hipStream_t stream) {
    const float* x  = (const float*)d_in[0];
    const float* wg = (const float*)d_in[1];
    const float* mk = (const float*)d_in[2];
    float* out = (float*)d_out;

    size_t need = XT_ELEMS * 2 + WT_ELEMS * 2 + 256;
    if (ws_size < need) {
        int total = NIMG * COUT * PIXIMG;
        k_naive<<<(total + 255) / 256, 256, 0, stream>>>(x, wg, mk, out, total);
        return;
    }

    unsigned short* xt = (unsigned short*)d_ws;
    unsigned short* wt = (unsigned short*)((char*)d_ws + XT_ELEMS * 2);

    k_transpose<<<NIMG * HP * 4, 256, 0, stream>>>(x, xt); // writes full xt incl. halo
    k_prepw<<<(COUT * CIN) / 256, 256, 0, stream>>>(wg, mk, wt);
    k_conv<<<TOTPIX / 256, 512, 0, stream>>>(xt, wt, out);
}

// Round 4
// 187.707 us; speedup vs baseline: 1.0269x; 1.0269x over previous
//
#include <hip/hip_runtime.h>
#include <hip/hip_bf16.h>

typedef short short8 __attribute__((ext_vector_type(8)));
typedef float float4v __attribute__((ext_vector_type(4)));

#define NIMG 32
#define CIN 256
#define COUT 256
#define HH 56
#define WW 56
#define HP 58
#define WP 58
#define PIXIMG (HH * WW)          /* 3136 */
#define TOTPIX (NIMG * PIXIMG)    /* 100352 */
#define OUTSTRIDE_N (COUT * PIXIMG)

static constexpr size_t XT_ELEMS = (size_t)NIMG * HP * WP * CIN; // bf16
static constexpr size_t WT_ELEMS = (size_t)9 * COUT * CIN;       // bf16

// fp32 -> bf16 bits, round-to-nearest-even (finite inputs only)
static __device__ __forceinline__ unsigned short f2bf(float f) {
    unsigned int u = __builtin_bit_cast(unsigned int, f);
    u = (u + 0x7fffu + ((u >> 16) & 1u)) >> 16;
    return (unsigned short)u;
}

// async global(16B/lane) -> LDS (wave-uniform base + lane*16)
static __device__ __forceinline__ void gl16(const unsigned short* g, char* l) {
    __builtin_amdgcn_global_load_lds(
        (const __attribute__((address_space(1))) void*)g,
        (__attribute__((address_space(3))) void*)l, 16, 0, 0);
}

// ---------------------------------------------------------------------------
// x (NCHW fp32) -> x_t[n][h'][w'][ic] bf16, padded; halo zeroed in-kernel.
// ---------------------------------------------------------------------------
__global__ __launch_bounds__(256) void k_transpose(const float* __restrict__ x,
                                                   unsigned short* __restrict__ xt) {
    int b   = blockIdx.x;
    int icb = b & 3;
    int hp  = (b >> 2) % HP;    // padded output row 0..57
    int n   = b / (4 * HP);
    unsigned short* rowb = xt + ((size_t)(n * HP + hp) * WP) * CIN + icb * 64;
    int t = threadIdx.x;

    if (hp == 0 || hp == HP - 1) {
        for (int idx = t; idx < WP * 8; idx += 256) {
            int wq = idx >> 3, q = idx & 7;
            *(uint4*)(rowb + (size_t)wq * CIN + q * 8) = (uint4){0, 0, 0, 0};
        }
        return;
    }
    int h = hp - 1;
    __shared__ __align__(16) char lds[64 * 128]; // [w 64][ic 64] bf16, swizzled
    int w = t & 63, icl0 = t >> 6;
    if (w < WW) {
        const float* src = x + ((size_t)(n * CIN + icb * 64 + icl0) * HH + h) * WW + w;
#pragma unroll
        for (int j = 0; j < 16; ++j) {
            float v = src[(size_t)(j * 4) * PIXIMG];
            int icl = icl0 + j * 4;
            *(unsigned short*)(lds + w * 128 + ((icl * 2) ^ ((w & 7) << 4))) = f2bf(v);
        }
    }
    __syncthreads();
    int ic4 = t & 15, wr = t >> 4;
    unsigned short* dst = rowb + (size_t)CIN + ic4 * 4; // w'=1 base
#pragma unroll
    for (int p = 0; p < 4; ++p) {
        int w2 = wr + p * 16;
        if (w2 < WW) {
            uint2 v = *(const uint2*)(lds + w2 * 128 + ((ic4 * 8) ^ ((w2 & 7) << 4)));
            *(uint2*)(dst + (size_t)w2 * CIN) = v;
        }
    }
    if (t < 32) { // zero w'=0 and w'=57 columns
        int col = (t >> 4) * (WP - 1);
        *(uint2*)(rowb + (size_t)col * CIN + (t & 15) * 4) = (uint2){0, 0};
    }
}

// ---------------------------------------------------------------------------
// wt[tap][oc][ic] = bf16(weight * mask)
// ---------------------------------------------------------------------------
__global__ __launch_bounds__(256) void k_prepw(const float* __restrict__ wgt,
                                               const float* __restrict__ msk,
                                               unsigned short* __restrict__ wt) {
    int t = blockIdx.x * 256 + threadIdx.x; // t = oc*256 + ic
    const float* wp = wgt + (size_t)t * 9;
    const float* mp = msk + (size_t)t * 9;
#pragma unroll
    for (int tap = 0; tap < 9; ++tap)
        wt[(size_t)tap * (COUT * CIN) + t] = f2bf(wp[tap] * mp[tap]);
}

// K-step s (0..35) -> source offsets. tap = s>>2, ic-block = s&3.
static __device__ __forceinline__ int aofs(int s) {
    return ((s >> 2) << 16) + ((s & 3) << 6);
}
static __device__ __forceinline__ int bofs(int s) {
    int tap = s >> 2, dh = (tap * 86) >> 8, dw = tap - dh * 3;
    return (dh * WP + dw) * CIN + ((s & 3) << 6);
}

// ---------------------------------------------------------------------------
// Main conv: 9 shifted GEMMs as one K=2304 GEMM, 256x256 tile, 8-phase
// schedule with REPAIRED counted-vmcnt pipeline (stage->wait distance 2-3
// phases, stage->read 3-4.5 phases; 4 counted waits/iteration).
// 512 threads = 8 waves (2Mx4N), wave tile 128x64, BK=64, 36 K-steps.
// Slot s @ s*65536: A(H=0/1 16KB halves, I=0/1 8KB quarters) @0, B @32768.
// ---------------------------------------------------------------------------
__global__ __launch_bounds__(512, 2) void k_conv(const unsigned short* __restrict__ xt,
                                                 const unsigned short* __restrict__ wt,
                                                 float* __restrict__ out) {
    __shared__ __align__(16) char lds[131072];

    const int t    = threadIdx.x;
    const int lane = t & 63;
    const int wid  = t >> 6;
    const int wm   = wid >> 2;  // 0..1 : 128-oc half
    const int wn   = wid & 3;   // 0..3 : 64-pix quarter

    // XCD-aware swizzle: 392 blocks = 8 XCDs x 49
    const int b0    = blockIdx.x;
    const int ptile = (b0 & 7) * 49 + (b0 >> 3);

    // ---- staging addressing (pre-swizzled global sources, linear LDS dest) ----
    const int rl  = lane >> 3;                 // row-within-8 at dest
    const int sc  = ((lane & 7) ^ rl) * 8;     // inverse-swizzled src col (elems)
    const size_t aSrc = (size_t)(wid * 8 + rl) * CIN + sc;
    const unsigned short* bS[4];
#pragma unroll
    for (int j = 0; j < 4; ++j) {
        int pg  = ptile * 256 + j * 64 + wid * 8 + rl;
        int n   = pg / PIXIMG;
        int rem = pg - n * PIXIMG;
        int h   = rem / WW, w = rem - h * WW;
        bS[j] = xt + ((size_t)((n * HP + h) * WP + w)) * CIN + sc;
    }
    char* const ldsDst = lds + wid * 1024;

#define STG_A(S, H, I, AOFF) \
    gl16(wt + (AOFF) + (size_t)((H) * 32768 + (I) * 16384) + aSrc, \
         ldsDst + (S) * 65536 + (H) * 16384 + (I) * 8192)
#define STG_B(S, H, I, BOFF) \
    gl16(bS[(H) * 2 + (I)] + (BOFF), \
         ldsDst + (S) * 65536 + 32768 + (H) * 16384 + (I) * 8192)

    // ---- fragment read offsets ----
    const int l15 = lane & 15;
    const int lg  = lane >> 4;
    const int aRd = wm * 16384 + l15 * 128;
    const int bRd = 32768 + (wn >> 1) * 16384 + ((wn & 1) * 64 + l15) * 128;
    int cO[2];
    cO[0] = (lg * 16) ^ ((l15 & 7) << 4);
    cO[1] = (64 + lg * 16) ^ ((l15 & 7) << 4);

#define LD_A(AF, S, MBASE)                                                   \
    _Pragma("unroll") for (int mi_ = 0; mi_ < 4; ++mi_)                      \
    _Pragma("unroll") for (int kk_ = 0; kk_ < 2; ++kk_)                      \
        AF[mi_][kk_] = *(const short8*)(lds + (S) * 65536 + aRd +            \
                                        ((MBASE) + mi_) * 2048 + cO[kk_]);
#define LD_B(BF, S, NBASE)                                                   \
    _Pragma("unroll") for (int ni_ = 0; ni_ < 2; ++ni_)                      \
    _Pragma("unroll") for (int kk_ = 0; kk_ < 2; ++kk_)                      \
        BF[ni_][kk_] = *(const short8*)(lds + (S) * 65536 + bRd +            \
                                        ((NBASE) + ni_) * 2048 + cO[kk_]);

    // plain barrier + compiler-only memory fence (no sched_barrier pinning)
#define BAR do { asm volatile("" ::: "memory");                              \
                 __builtin_amdgcn_s_barrier();                               \
                 asm volatile("" ::: "memory"); } while (0)
#define VMW2 asm volatile("s_waitcnt vmcnt(2)" ::: "memory")
#define VMW4 asm volatile("s_waitcnt vmcnt(4)" ::: "memory")
#define VMW6 asm volatile("s_waitcnt vmcnt(6)" ::: "memory")
#define VMW0 asm volatile("s_waitcnt vmcnt(0)" ::: "memory")

#define QUAD(MB, NB, AF, BF) do {                                            \
    __builtin_amdgcn_s_setprio(1);                                           \
    _Pragma("unroll") for (int kk_ = 0; kk_ < 2; ++kk_)                      \
    _Pragma("unroll") for (int mi_ = 0; mi_ < 4; ++mi_)                      \
    _Pragma("unroll") for (int ni_ = 0; ni_ < 2; ++ni_)                      \
        acc[(MB) + mi_][(NB) + ni_] = __builtin_amdgcn_mfma_f32_16x16x32_bf16( \
            AF[mi_][kk_], BF[ni_][kk_], acc[(MB) + mi_][(NB) + ni_], 0, 0, 0); \
    __builtin_amdgcn_s_setprio(0);                                           \
} while (0)

    float4v acc[8][4];
#pragma unroll
    for (int i = 0; i < 8; ++i)
#pragma unroll
        for (int j = 0; j < 4; ++j)
            acc[i][j] = (float4v){0.f, 0.f, 0.f, 0.f};

    // ---- prologue: slot0 <- step0 (8 quarters), slot1 B(H0) <- step1 ----
    STG_B(0, 0, 0, 0); STG_B(0, 0, 1, 0); STG_B(0, 1, 0, 0); STG_B(0, 1, 1, 0);
    STG_A(0, 0, 0, 0); STG_A(0, 1, 0, 0); STG_A(0, 0, 1, 0); STG_A(0, 1, 1, 0);
    {
        const int b1 = bofs(1);
        STG_B(1, 0, 0, b1); STG_B(1, 0, 1, b1);
    }
    VMW2; BAR;   // slot0 fully landed; 2 in flight (slot1 B.H0)

    // ---- main loop: 18 iterations x 2 K-steps, 8 phases ----
    // Stage ledger (steady state, outstanding after each wait in braces):
    //  slot1(step 2it+1): B.H0@prev-ph8, B.H1@ph1, A.lo@ph2, A.hi@ph3
    //  slot0(step 2it+2): B.H0@ph4, B.H1@ph5, A.lo@ph6, A.hi@ph7
    //  waits: VMW6@ph2 drains prev-ph7 (slot0 A.hi, read ph3)      {6}
    //         VMW4@ph4 drains prev-ph8,ph1,ph2 (slot1 B+A.lo, ph5) {4}
    //         VMW6@ph6 drains ph3 (slot1 A.hi, read ph7)           {6}
    //         VMW4@ph8 drains ph4,ph5,ph6 (slot0 B+A.lo, next ph1) {4}
#pragma unroll 1
    for (int it = 0; it < 18; ++it) {
        const int sO1 = 2 * it + 1;
        const int sE2 = (it < 17) ? 2 * it + 2 : 0; // wrap: lands, never read
        const int sO3 = (it < 17) ? 2 * it + 3 : 1;
        const int aO1 = aofs(sO1), bO1 = bofs(sO1);
        const int aO2 = aofs(sE2), bO2 = bofs(sE2);
        const int bO3 = bofs(sO3);

        short8 afl[4][2], afh[4][2], bfl[2][2], bfh[2][2];

        // ph1: read slot0 A.lo+B.lo; stage slot1 B.H1
        LD_A(afl, 0, 0); LD_B(bfl, 0, 0);
        STG_B(1, 1, 0, bO1); STG_B(1, 1, 1, bO1);
        BAR; QUAD(0, 0, afl, bfl); BAR;
        // ph2: read slot0 B.hi; stage slot1 A.lo; drain slot0 A.hi
        LD_B(bfh, 0, 2);
        STG_A(1, 0, 0, aO1); STG_A(1, 1, 0, aO1);
        VMW6; BAR; QUAD(0, 2, afl, bfh); BAR;
        // ph3: read slot0 A.hi; stage slot1 A.hi
        LD_A(afh, 0, 4);
        STG_A(1, 0, 1, aO1); STG_A(1, 1, 1, aO1);
        BAR; QUAD(4, 2, afh, bfh); BAR;
        // ph4: stage slot0' B.H0; drain slot1 B+A.lo
        STG_B(0, 0, 0, bO2); STG_B(0, 0, 1, bO2);
        VMW4; BAR; QUAD(4, 0, afh, bfl); BAR;
        // ph5: read slot1 A.lo+B.lo; stage slot0' B.H1
        LD_A(afl, 1, 0); LD_B(bfl, 1, 0);
        STG_B(0, 1, 0, bO2); STG_B(0, 1, 1, bO2);
        BAR; QUAD(0, 0, afl, bfl); BAR;
        // ph6: read slot1 B.hi; stage slot0' A.lo; drain slot1 A.hi
        LD_B(bfh, 1, 2);
        STG_A(0, 0, 0, aO2); STG_A(0, 1, 0, aO2);
        VMW6; BAR; QUAD(0, 2, afl, bfh); BAR;
        // ph7: read slot1 A.hi; stage slot0' A.hi
        LD_A(afh, 1, 4);
        STG_A(0, 0, 1, aO2); STG_A(0, 1, 1, aO2);
        BAR; QUAD(4, 2, afh, bfh); BAR;
        // ph8: stage slot1'' B.H0; drain slot0' B+A.lo
        STG_B(1, 0, 0, bO3); STG_B(1, 0, 1, bO3);
        VMW4; BAR; QUAD(4, 0, afh, bfl); BAR;
    }
#undef STG_A
#undef STG_B
#undef LD_A
#undef LD_B
#undef QUAD

    // ---- epilogue: drain async stages, LDS-transpose, coalesced stores ----
    VMW0;
    __syncthreads();
    float* ep = (float*)lds; // chunk: [128 oc][256 pix] f32, XOR-swizzled
#pragma unroll 1
    for (int c = 0; c < 2; ++c) {
        if (wm == c) {
#pragma unroll
            for (int mi = 0; mi < 8; ++mi)
#pragma unroll
                for (int ni = 0; ni < 4; ++ni)
#pragma unroll
                    for (int r = 0; r < 4; ++r) {
                        int row = mi * 16 + lg * 4 + r;
                        int pix = wn * 64 + ni * 16 + l15;
                        ep[row * 256 + (pix ^ ((row & 7) << 2))] = acc[mi][ni][r];
                    }
        }
        __syncthreads();
        const int row0 = t >> 6;
        const int c16  = t & 63;
#pragma unroll
        for (int p = 0; p < 16; ++p) {
            int row = p * 8 + row0;
            float4v v = *(const float4v*)&ep[row * 256 + ((c16 * 4) ^ ((row & 7) << 2))];
            int oc  = c * 128 + row;
            int pg  = ptile * 256 + c16 * 4;
            int n2  = pg / PIXIMG;
            int rem = pg - n2 * PIXIMG; // 3136%4==0: float4 stays in-image
            *(float4v*)(out + (size_t)n2 * OUTSTRIDE_N + (size_t)oc * PIXIMG + rem) = v;
        }
        if (c == 0) __syncthreads();
    }
}

// ---------------------------------------------------------------------------
// Fallback (ws too small): direct fp32 conv, slow but correct
// ---------------------------------------------------------------------------
__global__ __launch_bounds__(256) void k_naive(const float* __restrict__ x,
                                               const float* __restrict__ wg,
                                               const float* __restrict__ mk,
                                               float* __restrict__ out, int total) {
    int idx = blockIdx.x * 256 + threadIdx.x;
    if (idx >= total) return;
    int w  = idx % WW;
    int h  = (idx / WW) % HH;
    int oc = (idx / PIXIMG) % COUT;
    int n  = idx / (COUT * PIXIMG);
    float s = 0.f;
    for (int ic = 0; ic < CIN; ++ic) {
        const float* xp = x + (size_t)(n * CIN + ic) * PIXIMG;
        const float* wp = wg + (size_t)(oc * CIN + ic) * 9;
        const float* mp = mk + (size_t)(oc * CIN + ic) * 9;
#pragma unroll
        for (int kh = 0; kh < 3; ++kh) {
            int hy = h + kh - 1;
            if ((unsigned)hy >= HH) continue;
#pragma unroll
            for (int kw = 0; kw < 3; ++kw) {
                int wx = w + kw - 1;
                if ((unsigned)wx >= WW) continue;
                s += xp[hy * WW + wx] * wp[kh * 3 + kw] * mp[kh * 3 + kw];
            }
        }
    }
    out[idx] = s;
}

extern "C" void kernel_launch(void* const* d_in, const int* in_sizes, int n_in,
                              void* d_out, int out_size, void* d_ws, size_t ws_size,
                              hipStream_t stream) {
    const float* x  = (const float*)d_in[0];
    const float* wg = (const float*)d_in[1];
    const float* mk = (const float*)d_in[2];
    float* out = (float*)d_out;

    size_t need = XT_ELEMS * 2 + WT_ELEMS * 2 + 256;
    if (ws_size < need) {
        int total = NIMG * COUT * PIXIMG;
        k_naive<<<(total + 255) / 256, 256, 0, stream>>>(x, wg, mk, out, total);
        return;
    }

    unsigned short* xt = (unsigned short*)d_ws;
    unsigned short* wt = (unsigned short*)((char*)d_ws + XT_ELEMS * 2);

    k_transpose<<<NIMG * HP * 4, 256, 0, stream>>>(x, xt);
    k_prepw<<<(COUT * CIN) / 256, 256, 0, stream>>>(wg, mk, wt);
    k_conv<<<TOTPIX / 256, 512, 0, stream>>>(xt, wt, out);
}

// Round 5
// 152.486 us; speedup vs baseline: 1.2640x; 1.2310x over previous
//
#include <hip/hip_runtime.h>
#include <hip/hip_bf16.h>

typedef short short8 __attribute__((ext_vector_type(8)));
typedef float float4v __attribute__((ext_vector_type(4)));

#define NIMG 32
#define CIN 256
#define COUT 256
#define HH 56
#define WW 56
#define HP 58
#define WP 58
#define PIXIMG (HH * WW)          /* 3136 */
#define TOTPIX (NIMG * PIXIMG)    /* 100352 */
#define OUTSTRIDE_N (COUT * PIXIMG)

static constexpr size_t XT_ELEMS = (size_t)NIMG * HP * WP * CIN; // bf16
static constexpr size_t WT_ELEMS = (size_t)9 * COUT * CIN;       // bf16

// fp32 -> bf16 bits, round-to-nearest-even (finite inputs only)
static __device__ __forceinline__ unsigned short f2bf(float f) {
    unsigned int u = __builtin_bit_cast(unsigned int, f);
    u = (u + 0x7fffu + ((u >> 16) & 1u)) >> 16;
    return (unsigned short)u;
}

// async global(16B/lane) -> LDS (wave-uniform base + lane*16)
static __device__ __forceinline__ void gl16(const unsigned short* g, char* l) {
    __builtin_amdgcn_global_load_lds(
        (const __attribute__((address_space(1))) void*)g,
        (__attribute__((address_space(3))) void*)l, 16, 0, 0);
}

// ---------------------------------------------------------------------------
// x (NCHW fp32) -> x_t[n][h'][w'][ic] bf16, padded; halo zeroed in-kernel.
// ---------------------------------------------------------------------------
__global__ __launch_bounds__(256) void k_transpose(const float* __restrict__ x,
                                                   unsigned short* __restrict__ xt) {
    int b   = blockIdx.x;
    int icb = b & 3;
    int hp  = (b >> 2) % HP;    // padded output row 0..57
    int n   = b / (4 * HP);
    unsigned short* rowb = xt + ((size_t)(n * HP + hp) * WP) * CIN + icb * 64;
    int t = threadIdx.x;

    if (hp == 0 || hp == HP - 1) {
        for (int idx = t; idx < WP * 8; idx += 256) {
            int wq = idx >> 3, q = idx & 7;
            *(uint4*)(rowb + (size_t)wq * CIN + q * 8) = (uint4){0, 0, 0, 0};
        }
        return;
    }
    int h = hp - 1;
    __shared__ __align__(16) char lds[64 * 128]; // [w 64][ic 64] bf16, swizzled
    int w = t & 63, icl0 = t >> 6;
    if (w < WW) {
        const float* src = x + ((size_t)(n * CIN + icb * 64 + icl0) * HH + h) * WW + w;
#pragma unroll
        for (int j = 0; j < 16; ++j) {
            float v = src[(size_t)(j * 4) * PIXIMG];
            int icl = icl0 + j * 4;
            *(unsigned short*)(lds + w * 128 + ((icl * 2) ^ ((w & 7) << 4))) = f2bf(v);
        }
    }
    __syncthreads();
    int ic4 = t & 15, wr = t >> 4;
    unsigned short* dst = rowb + (size_t)CIN + ic4 * 4; // w'=1 base
#pragma unroll
    for (int p = 0; p < 4; ++p) {
        int w2 = wr + p * 16;
        if (w2 < WW) {
            uint2 v = *(const uint2*)(lds + w2 * 128 + ((ic4 * 8) ^ ((w2 & 7) << 4)));
            *(uint2*)(dst + (size_t)w2 * CIN) = v;
        }
    }
    if (t < 32) { // zero w'=0 and w'=57 columns
        int col = (t >> 4) * (WP - 1);
        *(uint2*)(rowb + (size_t)col * CIN + (t & 15) * 4) = (uint2){0, 0};
    }
}

// ---------------------------------------------------------------------------
// wt[tap][oc][ic] = bf16(weight * mask)
// ---------------------------------------------------------------------------
__global__ __launch_bounds__(256) void k_prepw(const float* __restrict__ wgt,
                                               const float* __restrict__ msk,
                                               unsigned short* __restrict__ wt) {
    int t = blockIdx.x * 256 + threadIdx.x; // t = oc*256 + ic
    const float* wp = wgt + (size_t)t * 9;
    const float* mp = msk + (size_t)t * 9;
#pragma unroll
    for (int tap = 0; tap < 9; ++tap)
        wt[(size_t)tap * (COUT * CIN) + t] = f2bf(wp[tap] * mp[tap]);
}

// ---------------------------------------------------------------------------
// Main conv: 9 shifted GEMMs, m97 structure: 128x128 tile, 4 waves (2x2),
// BK=64, SINGLE 32KB A+B buffer, {STAGE; sync; COMPUTE; sync} per K-step.
// LDS 33792B total (epilogue [64][132] f32 aliases the buffer) -> 3 blocks/CU
// (VGPR-capped at launch_bounds(256,3)); cross-block wave overlap absorbs
// the per-step vmcnt(0) barrier drains (m97/m114 regime).
// ---------------------------------------------------------------------------
__global__ __launch_bounds__(256, 3) void k_conv(const unsigned short* __restrict__ xt,
                                                 const unsigned short* __restrict__ wt,
                                                 float* __restrict__ out) {
    __shared__ __align__(16) char lds[64 * 132 * 4]; // 33792 B
    // K-loop uses first 32KB: A [128 oc][64 ic] @0, B [128 pix][64 ic] @16384

    const int t    = threadIdx.x;
    const int lane = t & 63;
    const int wid  = t >> 6;
    const int woc  = wid >> 1; // 64-oc half
    const int wpx  = wid & 1;  // 64-pix half

    // XCD-aware chunked swizzle: 1568 blocks = 8 XCDs x 196
    const int b0 = blockIdx.x;
    const int b  = (b0 & 7) * 196 + (b0 >> 3);
    const int ptile = b >> 1;
    const int ocb   = b & 1;

    // ---- staging: wave stages rows [wid*32, +32) of A and B; 4 gl16 each ----
    const int rl  = lane >> 3;                 // row-within-8 at dest
    const int sc  = ((lane & 7) ^ rl) * 8;     // inverse-swizzled src col (elems)
    const unsigned short* aS[4];
    const unsigned short* bS[4];
    char* dA[4];
    char* dB[4];
#pragma unroll
    for (int c = 0; c < 4; ++c) {
        int r = wid * 32 + c * 8 + rl;
        aS[c] = wt + (size_t)(ocb * 128 + r) * CIN + sc;
        int pg  = ptile * 128 + r;
        int n   = pg / PIXIMG;
        int rem = pg - n * PIXIMG;
        int h   = rem / WW, w = rem - h * WW;
        bS[c] = xt + ((size_t)((n * HP + h) * WP + w)) * CIN + sc;
        dA[c] = lds + (wid * 32 + c * 8) * 128;
        dB[c] = lds + 16384 + (wid * 32 + c * 8) * 128;
    }

    // ---- fragment read offsets ----
    const int l15  = lane & 15;
    const int lg   = lane >> 4;
    const int swzf = (lane & 7) << 4;
    int colk[2];
    colk[0] = (lg * 16) ^ swzf;
    colk[1] = (64 + lg * 16) ^ swzf;
    int rowA[4], rowB[4];
#pragma unroll
    for (int i = 0; i < 4; ++i) {
        rowA[i] = (woc * 64 + i * 16 + l15) * 128;
        rowB[i] = 16384 + (wpx * 64 + i * 16 + l15) * 128;
    }

    float4v acc[4][4];
#pragma unroll
    for (int i = 0; i < 4; ++i)
#pragma unroll
        for (int j = 0; j < 4; ++j)
            acc[i][j] = (float4v){0.f, 0.f, 0.f, 0.f};

    // ---- main loop: 36 K-steps, single-buffered (m97 structure) ----
#pragma unroll 1
    for (int s = 0; s < 36; ++s) {
        const int tap = s >> 2;
        const int dh  = (tap * 86) >> 8;
        const int dw  = tap - dh * 3;
        const size_t ao = (size_t)tap * (COUT * CIN) + (size_t)((s & 3) << 6);
        const size_t bo = (size_t)(dh * WP + dw) * CIN + (size_t)((s & 3) << 6);
#pragma unroll
        for (int c = 0; c < 4; ++c) gl16(aS[c] + ao, dA[c]);
#pragma unroll
        for (int c = 0; c < 4; ++c) gl16(bS[c] + bo, dB[c]);
        __syncthreads(); // vmcnt(0) drain + barrier: buffer ready
#pragma unroll
        for (int kk = 0; kk < 2; ++kk) {
            short8 af[4], bfr[4];
#pragma unroll
            for (int i = 0; i < 4; ++i)
                af[i] = *(const short8*)(lds + rowA[i] + colk[kk]);
#pragma unroll
            for (int i = 0; i < 4; ++i)
                bfr[i] = *(const short8*)(lds + rowB[i] + colk[kk]);
#pragma unroll
            for (int oi = 0; oi < 4; ++oi)
#pragma unroll
                for (int pi = 0; pi < 4; ++pi)
                    acc[oi][pi] = __builtin_amdgcn_mfma_f32_16x16x32_bf16(
                        af[oi], bfr[pi], acc[oi][pi], 0, 0, 0);
        }
        __syncthreads(); // reads done before next stage overwrites
    }

    // ---- epilogue: 2 chunks of 64 oc via LDS transpose, coalesced stores ----
    float* ep = (float*)lds; // [64 oc][132] f32, pad kills write conflicts
#pragma unroll 1
    for (int c = 0; c < 2; ++c) {
        if (woc == c) {
#pragma unroll
            for (int oi = 0; oi < 4; ++oi)
#pragma unroll
                for (int pi = 0; pi < 4; ++pi)
#pragma unroll
                    for (int r = 0; r < 4; ++r)
                        ep[(oi * 16 + lg * 4 + r) * 132 +
                           (wpx * 64 + pi * 16 + l15)] = acc[oi][pi][r];
        }
        __syncthreads();
        const int rrow = t >> 5;        // 0..7
        const int rcol = (t & 31) * 4;  // 0..124
        int pg  = ptile * 128 + rcol;
        int n2  = pg / PIXIMG;
        int rem = pg - n2 * PIXIMG;     // 3136%4==0: float4 stays in-image
        float* ob = out + (size_t)n2 * OUTSTRIDE_N +
                    (size_t)(ocb * 128 + c * 64) * PIXIMG + rem;
#pragma unroll
        for (int rd = 0; rd < 8; ++rd) {
            int row = rd * 8 + rrow;    // 0..63
            float4v v = *(const float4v*)&ep[row * 132 + rcol];
            *(float4v*)(ob + (size_t)row * PIXIMG) = v;
        }
        __syncthreads(); // chunk reads done before next chunk's writes
    }
}

// ---------------------------------------------------------------------------
// Fallback (ws too small): direct fp32 conv, slow but correct
// ---------------------------------------------------------------------------
__global__ __launch_bounds__(256) void k_naive(const float* __restrict__ x,
                                               const float* __restrict__ wg,
                                               const float* __restrict__ mk,
                                               float* __restrict__ out, int total) {
    int idx = blockIdx.x * 256 + threadIdx.x;
    if (idx >= total) return;
    int w  = idx % WW;
    int h  = (idx / WW) % HH;
    int oc = (idx / PIXIMG) % COUT;
    int n  = idx / (COUT * PIXIMG);
    float s = 0.f;
    for (int ic = 0; ic < CIN; ++ic) {
        const float* xp = x + (size_t)(n * CIN + ic) * PIXIMG;
        const float* wp = wg + (size_t)(oc * CIN + ic) * 9;
        const float* mp = mk + (size_t)(oc * CIN + ic) * 9;
#pragma unroll
        for (int kh = 0; kh < 3; ++kh) {
            int hy = h + kh - 1;
            if ((unsigned)hy >= HH) continue;
#pragma unroll
            for (int kw = 0; kw < 3; ++kw) {
                int wx = w + kw - 1;
                if ((unsigned)wx >= WW) continue;
                s += xp[hy * WW + wx] * wp[kh * 3 + kw] * mp[kh * 3 + kw];
            }
        }
    }
    out[idx] = s;
}

extern "C" void kernel_launch(void* const* d_in, const int* in_sizes, int n_in,
                              void* d_out, int out_size, void* d_ws, size_t ws_size,
                              hipStream_t stream) {
    const float* x  = (const float*)d_in[0];
    const float* wg = (const float*)d_in[1];
    const float* mk = (const float*)d_in[2];
    float* out = (float*)d_out;

    size_t need = XT_ELEMS * 2 + WT_ELEMS * 2 + 256;
    if (ws_size < need) {
        int total = NIMG * COUT * PIXIMG;
        k_naive<<<(total + 255) / 256, 256, 0, stream>>>(x, wg, mk, out, total);
        return;
    }

    unsigned short* xt = (unsigned short*)d_ws;
    unsigned short* wt = (unsigned short*)((char*)d_ws + XT_ELEMS * 2);

    k_transpose<<<NIMG * HP * 4, 256, 0, stream>>>(x, xt);
    k_prepw<<<(COUT * CIN) / 256, 256, 0, stream>>>(wg, mk, wt);
    k_conv<<<(TOTPIX / 128) * 2, 256, 0, stream>>>(xt, wt, out);
}

// Round 6
// 152.214 us; speedup vs baseline: 1.2663x; 1.0018x over previous
//
#include <hip/hip_runtime.h>
#include <hip/hip_bf16.h>

typedef short short8 __attribute__((ext_vector_type(8)));
typedef float float4v __attribute__((ext_vector_type(4)));

#define NIMG 32
#define CIN 256
#define COUT 256
#define HH 56
#define WW 56
#define HP 58
#define WP 58
#define PIXIMG (HH * WW)          /* 3136 */
#define TOTPIX (NIMG * PIXIMG)    /* 100352 */
#define OUTSTRIDE_N (COUT * PIXIMG)

static constexpr size_t XT_ELEMS = (size_t)NIMG * HP * WP * CIN; // bf16
static constexpr size_t WT_ELEMS = (size_t)9 * COUT * CIN;       // bf16

// fp32 -> bf16 bits, round-to-nearest-even (finite inputs only)
static __device__ __forceinline__ unsigned short f2bf(float f) {
    unsigned int u = __builtin_bit_cast(unsigned int, f);
    u = (u + 0x7fffu + ((u >> 16) & 1u)) >> 16;
    return (unsigned short)u;
}

// async global(16B/lane) -> LDS (wave-uniform base + lane*16)
static __device__ __forceinline__ void gl16(const unsigned short* g, char* l) {
    __builtin_amdgcn_global_load_lds(
        (const __attribute__((address_space(1))) void*)g,
        (__attribute__((address_space(3))) void*)l, 16, 0, 0);
}

// ---------------------------------------------------------------------------
// x (NCHW fp32) -> x_t[n][h'][w'][ic] bf16, padded; halo zeroed in-kernel.
// ---------------------------------------------------------------------------
__global__ __launch_bounds__(256) void k_transpose(const float* __restrict__ x,
                                                   unsigned short* __restrict__ xt) {
    int b   = blockIdx.x;
    int icb = b & 3;
    int hp  = (b >> 2) % HP;    // padded output row 0..57
    int n   = b / (4 * HP);
    unsigned short* rowb = xt + ((size_t)(n * HP + hp) * WP) * CIN + icb * 64;
    int t = threadIdx.x;

    if (hp == 0 || hp == HP - 1) {
        for (int idx = t; idx < WP * 8; idx += 256) {
            int wq = idx >> 3, q = idx & 7;
            *(uint4*)(rowb + (size_t)wq * CIN + q * 8) = (uint4){0, 0, 0, 0};
        }
        return;
    }
    int h = hp - 1;
    __shared__ __align__(16) char lds[64 * 128]; // [w 64][ic 64] bf16, swizzled
    int w = t & 63, icl0 = t >> 6;
    if (w < WW) {
        const float* src = x + ((size_t)(n * CIN + icb * 64 + icl0) * HH + h) * WW + w;
#pragma unroll
        for (int j = 0; j < 16; ++j) {
            float v = src[(size_t)(j * 4) * PIXIMG];
            int icl = icl0 + j * 4;
            *(unsigned short*)(lds + w * 128 + ((icl * 2) ^ ((w & 7) << 4))) = f2bf(v);
        }
    }
    __syncthreads();
    int ic4 = t & 15, wr = t >> 4;
    unsigned short* dst = rowb + (size_t)CIN + ic4 * 4; // w'=1 base
#pragma unroll
    for (int p = 0; p < 4; ++p) {
        int w2 = wr + p * 16;
        if (w2 < WW) {
            uint2 v = *(const uint2*)(lds + w2 * 128 + ((ic4 * 8) ^ ((w2 & 7) << 4)));
            *(uint2*)(dst + (size_t)w2 * CIN) = v;
        }
    }
    if (t < 32) { // zero w'=0 and w'=57 columns
        int col = (t >> 4) * (WP - 1);
        *(uint2*)(rowb + (size_t)col * CIN + (t & 15) * 4) = (uint2){0, 0};
    }
}

// ---------------------------------------------------------------------------
// wt[tap][oc][ic] = bf16(weight * mask)
// ---------------------------------------------------------------------------
__global__ __launch_bounds__(256) void k_prepw(const float* __restrict__ wgt,
                                               const float* __restrict__ msk,
                                               unsigned short* __restrict__ wt) {
    int t = blockIdx.x * 256 + threadIdx.x; // t = oc*256 + ic
    const float* wp = wgt + (size_t)t * 9;
    const float* mp = msk + (size_t)t * 9;
#pragma unroll
    for (int tap = 0; tap < 9; ++tap)
        wt[(size_t)tap * (COUT * CIN) + t] = f2bf(wp[tap] * mp[tap]);
}

// ---------------------------------------------------------------------------
// Main conv: 9 shifted GEMMs, m97 structure: 128x128 tile, 4 waves (2x2),
// BK=64, SINGLE 32KB A+B buffer, {STAGE; sync; COMPUTE; sync} per K-step.
// LDS 33792B -> 4 blocks/CU (135KB of 160KB; VGPR 60 << 128-cap for 16
// waves/CU). Round-6 single-variable change: launch_bounds (256,3)->(256,4);
// cross-block wave overlap absorbs the per-step vmcnt(0) drains (m114).
// ---------------------------------------------------------------------------
__global__ __launch_bounds__(256, 4) void k_conv(const unsigned short* __restrict__ xt,
                                                 const unsigned short* __restrict__ wt,
                                                 float* __restrict__ out) {
    __shared__ __align__(16) char lds[64 * 132 * 4]; // 33792 B
    // K-loop uses first 32KB: A [128 oc][64 ic] @0, B [128 pix][64 ic] @16384

    const int t    = threadIdx.x;
    const int lane = t & 63;
    const int wid  = t >> 6;
    const int woc  = wid >> 1; // 64-oc half
    const int wpx  = wid & 1;  // 64-pix half

    // XCD-aware chunked swizzle: 1568 blocks = 8 XCDs x 196
    const int b0 = blockIdx.x;
    const int b  = (b0 & 7) * 196 + (b0 >> 3);
    const int ptile = b >> 1;
    const int ocb   = b & 1;

    // ---- staging: wave stages rows [wid*32, +32) of A and B; 4 gl16 each ----
    const int rl  = lane >> 3;                 // row-within-8 at dest
    const int sc  = ((lane & 7) ^ rl) * 8;     // inverse-swizzled src col (elems)
    const unsigned short* aS[4];
    const unsigned short* bS[4];
    char* dA[4];
    char* dB[4];
#pragma unroll
    for (int c = 0; c < 4; ++c) {
        int r = wid * 32 + c * 8 + rl;
        aS[c] = wt + (size_t)(ocb * 128 + r) * CIN + sc;
        int pg  = ptile * 128 + r;
        int n   = pg / PIXIMG;
        int rem = pg - n * PIXIMG;
        int h   = rem / WW, w = rem - h * WW;
        bS[c] = xt + ((size_t)((n * HP + h) * WP + w)) * CIN + sc;
        dA[c] = lds + (wid * 32 + c * 8) * 128;
        dB[c] = lds + 16384 + (wid * 32 + c * 8) * 128;
    }

    // ---- fragment read offsets ----
    const int l15  = lane & 15;
    const int lg   = lane >> 4;
    const int swzf = (lane & 7) << 4;
    int colk[2];
    colk[0] = (lg * 16) ^ swzf;
    colk[1] = (64 + lg * 16) ^ swzf;
    int rowA[4], rowB[4];
#pragma unroll
    for (int i = 0; i < 4; ++i) {
        rowA[i] = (woc * 64 + i * 16 + l15) * 128;
        rowB[i] = 16384 + (wpx * 64 + i * 16 + l15) * 128;
    }

    float4v acc[4][4];
#pragma unroll
    for (int i = 0; i < 4; ++i)
#pragma unroll
        for (int j = 0; j < 4; ++j)
            acc[i][j] = (float4v){0.f, 0.f, 0.f, 0.f};

    // ---- main loop: 36 K-steps, single-buffered (m97 structure) ----
#pragma unroll 1
    for (int s = 0; s < 36; ++s) {
        const int tap = s >> 2;
        const int dh  = (tap * 86) >> 8;
        const int dw  = tap - dh * 3;
        const size_t ao = (size_t)tap * (COUT * CIN) + (size_t)((s & 3) << 6);
        const size_t bo = (size_t)(dh * WP + dw) * CIN + (size_t)((s & 3) << 6);
#pragma unroll
        for (int c = 0; c < 4; ++c) gl16(aS[c] + ao, dA[c]);
#pragma unroll
        for (int c = 0; c < 4; ++c) gl16(bS[c] + bo, dB[c]);
        __syncthreads(); // vmcnt(0) drain + barrier: buffer ready
#pragma unroll
        for (int kk = 0; kk < 2; ++kk) {
            short8 af[4], bfr[4];
#pragma unroll
            for (int i = 0; i < 4; ++i)
                af[i] = *(const short8*)(lds + rowA[i] + colk[kk]);
#pragma unroll
            for (int i = 0; i < 4; ++i)
                bfr[i] = *(const short8*)(lds + rowB[i] + colk[kk]);
#pragma unroll
            for (int oi = 0; oi < 4; ++oi)
#pragma unroll
                for (int pi = 0; pi < 4; ++pi)
                    acc[oi][pi] = __builtin_amdgcn_mfma_f32_16x16x32_bf16(
                        af[oi], bfr[pi], acc[oi][pi], 0, 0, 0);
        }
        __syncthreads(); // reads done before next stage overwrites
    }

    // ---- epilogue: 2 chunks of 64 oc via LDS transpose, coalesced stores ----
    float* ep = (float*)lds; // [64 oc][132] f32, pad kills write conflicts
#pragma unroll 1
    for (int c = 0; c < 2; ++c) {
        if (woc == c) {
#pragma unroll
            for (int oi = 0; oi < 4; ++oi)
#pragma unroll
                for (int pi = 0; pi < 4; ++pi)
#pragma unroll
                    for (int r = 0; r < 4; ++r)
                        ep[(oi * 16 + lg * 4 + r) * 132 +
                           (wpx * 64 + pi * 16 + l15)] = acc[oi][pi][r];
        }
        __syncthreads();
        const int rrow = t >> 5;        // 0..7
        const int rcol = (t & 31) * 4;  // 0..124
        int pg  = ptile * 128 + rcol;
        int n2  = pg / PIXIMG;
        int rem = pg - n2 * PIXIMG;     // 3136%4==0: float4 stays in-image
        float* ob = out + (size_t)n2 * OUTSTRIDE_N +
                    (size_t)(ocb * 128 + c * 64) * PIXIMG + rem;
#pragma unroll
        for (int rd = 0; rd < 8; ++rd) {
            int row = rd * 8 + rrow;    // 0..63
            float4v v = *(const float4v*)&ep[row * 132 + rcol];
            *(float4v*)(ob + (size_t)row * PIXIMG) = v;
        }
        __syncthreads(); // chunk reads done before next chunk's writes
    }
}

// ---------------------------------------------------------------------------
// Fallback (ws too small): direct fp32 conv, slow but correct
// ---------------------------------------------------------------------------
__global__ __launch_bounds__(256) void k_naive(const float* __restrict__ x,
                                               const float* __restrict__ wg,
                                               const float* __restrict__ mk,
                                               float* __restrict__ out, int total) {
    int idx = blockIdx.x * 256 + threadIdx.x;
    if (idx >= total) return;
    int w  = idx % WW;
    int h  = (idx / WW) % HH;
    int oc = (idx / PIXIMG) % COUT;
    int n  = idx / (COUT * PIXIMG);
    float s = 0.f;
    for (int ic = 0; ic < CIN; ++ic) {
        const float* xp = x + (size_t)(n * CIN + ic) * PIXIMG;
        const float* wp = wg + (size_t)(oc * CIN + ic) * 9;
        const float* mp = mk + (size_t)(oc * CIN + ic) * 9;
#pragma unroll
        for (int kh = 0; kh < 3; ++kh) {
            int hy = h + kh - 1;
            if ((unsigned)hy >= HH) continue;
#pragma unroll
            for (int kw = 0; kw < 3; ++kw) {
                int wx = w + kw - 1;
                if ((unsigned)wx >= WW) continue;
                s += xp[hy * WW + wx] * wp[kh * 3 + kw] * mp[kh * 3 + kw];
            }
        }
    }
    out[idx] = s;
}

extern "C" void kernel_launch(void* const* d_in, const int* in_sizes, int n_in,
                              void* d_out, int out_size, void* d_ws, size_t ws_size,
                              hipStream_t stream) {
    const float* x  = (const float*)d_in[0];
    const float* wg = (const float*)d_in[1];
    const float* mk = (const float*)d_in[2];
    float* out = (float*)d_out;

    size_t need = XT_ELEMS * 2 + WT_ELEMS * 2 + 256;
    if (ws_size < need) {
        int total = NIMG * COUT * PIXIMG;
        k_naive<<<(total + 255) / 256, 256, 0, stream>>>(x, wg, mk, out, total);
        return;
    }

    unsigned short* xt = (unsigned short*)d_ws;
    unsigned short* wt = (unsigned short*)((char*)d_ws + XT_ELEMS * 2);

    k_transpose<<<NIMG * HP * 4, 256, 0, stream>>>(x, xt);
    k_prepw<<<(COUT * CIN) / 256, 256, 0, stream>>>(wg, mk, wt);
    k_conv<<<(TOTPIX / 128) * 2, 256, 0, stream>>>(xt, wt, out);
}